// Round 5
// baseline (287.440 us; speedup 1.0000x reference)
//
#include <hip/hip_runtime.h>
#include <hip/hip_bf16.h>

namespace {
constexpr int NB = 2, NS = 2048, NH = 16, ND = 128;
constexpr int QB = 64, KB = 64;
constexpr int NQT = NS / QB;            // 32 q-tiles -> 16 balanced pairs
constexpr int ROWSTRIDE = NH * ND;      // 2048 floats between seq positions
constexpr float SCALE_LOG2E = 0.08838834764831843f * 1.4426950408889634f;

constexpr int K_OFF = 0;       // K tile  [64][128] bf16, 256B rows, swz ((r&7)<<4)
constexpr int V_OFF = 16384;   // Vt tile [128 d][64 k] bf16, 128B rows, swz (((d>>1)&7)<<4)
constexpr int P_OFF = 32768;   // per-wave P [16][72] bf16 (144B rows, padded)
constexpr int P_WSZ = 2304;
constexpr int SMEM_SZ = P_OFF + 4 * P_WSZ;  // 41984 B
}

typedef __attribute__((ext_vector_type(4))) float f32x4;
typedef __attribute__((ext_vector_type(8))) short bf16x8;
typedef __attribute__((ext_vector_type(2))) unsigned int u32x2;

__device__ __forceinline__ unsigned short f2bf(float f) {
  union { __hip_bfloat16 h; unsigned short u; } cv;
  cv.h = __float2bfloat16(f);
  return cv.u;
}

__device__ __forceinline__ float bcast_row(const float v[4], int lane) {
  int q = lane & 15;
  int src = ((q >> 2) << 4) | q;
  float a0 = __shfl(v[0], src, 64);
  float a1 = __shfl(v[1], src, 64);
  float a2 = __shfl(v[2], src, 64);
  float a3 = __shfl(v[3], src, 64);
  int r = q & 3;
  return (r == 0) ? a0 : ((r == 1) ? a1 : ((r == 2) ? a2 : a3));
}

__global__ __launch_bounds__(256)
void fattn_fwd(const float* __restrict__ Q, const float* __restrict__ K,
               const float* __restrict__ V, float* __restrict__ O) {
  __shared__ __align__(16) char smem[SMEM_SZ];

  // XCD-aware decode: hardware round-robins bid%8 across XCDs; give each XCD
  // 64 consecutive logical blocks (= 4 whole (b,h) slices) for L2 K/V reuse.
  const int bid = blockIdx.x;
  const int lid = (bid & 7) * 64 + (bid >> 3);
  const int pid = lid & 15;          // pair index -> q-tiles {pid, 31-pid}
  const int h = (lid >> 4) & 15;
  const int b = lid >> 8;

  const int t = threadIdx.x;
  const int w = t >> 6;
  const int lane = t & 63;
  const int g = lane >> 4;
  const int cc = lane & 15;

  const size_t bh = ((size_t)b * NS * NH + h) * (size_t)ND;

  char* Kl = smem + K_OFF;
  char* Vl = smem + V_OFF;
  char* Pl = smem + P_OFF + w * P_WSZ;

  // staging registers (reg double-buffer: loads for kt+1 fly during compute of kt)
  f32x4 kpre[8];
  f32x4 vpre[2][4];
  const int kc4 = t & 31;          // K: float4 column chunk
  const int kr = t >> 5;           // K: row base (8-row strides)
  const int vr0a = (t >> 5) * 4;   // V: first 4-row group
  const int vr0b = vr0a + 32;      // V: second 4-row group

  auto issue_loads = [&](int kb) {
#pragma unroll
    for (int jj = 0; jj < 8; ++jj)
      kpre[jj] = *reinterpret_cast<const f32x4*>(
          K + bh + (size_t)(kb + kr + jj * 8) * ROWSTRIDE + kc4 * 4);
#pragma unroll
    for (int j = 0; j < 4; ++j)
      vpre[0][j] = *reinterpret_cast<const f32x4*>(
          V + bh + (size_t)(kb + vr0a + j) * ROWSTRIDE + kc4 * 4);
#pragma unroll
    for (int j = 0; j < 4; ++j)
      vpre[1][j] = *reinterpret_cast<const f32x4*>(
          V + bh + (size_t)(kb + vr0b + j) * ROWSTRIDE + kc4 * 4);
  };

  for (int half = 0; half < 2; ++half) {
    const int qt = half ? (NQT - 1 - pid) : pid;

    // ---- Q fragments in registers: A[row=cc][d = dc*32 + 8g + i] ----
    bf16x8 qf[4];
    {
      const float* qp = Q + bh + (size_t)(qt * QB + w * 16 + cc) * ROWSTRIDE;
#pragma unroll
      for (int dc = 0; dc < 4; ++dc) {
        f32x4 v0 = *reinterpret_cast<const f32x4*>(qp + dc * 32 + 8 * g);
        f32x4 v1 = *reinterpret_cast<const f32x4*>(qp + dc * 32 + 8 * g + 4);
        bf16x8 f;
        f[0] = (short)f2bf(v0[0]); f[1] = (short)f2bf(v0[1]);
        f[2] = (short)f2bf(v0[2]); f[3] = (short)f2bf(v0[3]);
        f[4] = (short)f2bf(v1[0]); f[5] = (short)f2bf(v1[1]);
        f[6] = (short)f2bf(v1[2]); f[7] = (short)f2bf(v1[3]);
        qf[dc] = f;
      }
    }

    f32x4 oacc[8];  // O^T accumulator: row d = mt*16+4g+reg, col q = cc
#pragma unroll
    for (int i = 0; i < 8; ++i) { oacc[i][0] = 0.f; oacc[i][1] = 0.f; oacc[i][2] = 0.f; oacc[i][3] = 0.f; }
    float m_run[4] = {-1e30f, -1e30f, -1e30f, -1e30f};
    float l_run[4] = {0.f, 0.f, 0.f, 0.f};

    issue_loads(0);  // prologue: tile 0 in flight

    for (int kt = 0; kt <= qt; ++kt) {
      // ---- write staged tile kt to LDS (waits on its loads; converts to bf16) ----
#pragma unroll
      for (int jj = 0; jj < 8; ++jj) {
        int r = kr + jj * 8;
        unsigned int klo = (unsigned int)f2bf(kpre[jj][0]) | ((unsigned int)f2bf(kpre[jj][1]) << 16);
        unsigned int khi = (unsigned int)f2bf(kpre[jj][2]) | ((unsigned int)f2bf(kpre[jj][3]) << 16);
        int kbyte = (r * 256 + kc4 * 8) ^ ((r & 7) << 4);
        u32x2 kk; kk[0] = klo; kk[1] = khi;
        *reinterpret_cast<u32x2*>(Kl + kbyte) = kk;
      }
#pragma unroll
      for (int it = 0; it < 2; ++it) {
        int r0 = it ? vr0b : vr0a;
#pragma unroll
        for (int j = 0; j < 4; ++j) {
          int d = 4 * kc4 + j;
          unsigned int lo = (unsigned int)f2bf(vpre[it][0][j]) | ((unsigned int)f2bf(vpre[it][1][j]) << 16);
          unsigned int hi = (unsigned int)f2bf(vpre[it][2][j]) | ((unsigned int)f2bf(vpre[it][3][j]) << 16);
          int vbyte = (d * 128 + r0 * 2) ^ (((d >> 1) & 7) << 4);
          u32x2 pk; pk[0] = lo; pk[1] = hi;
          *reinterpret_cast<u32x2*>(Vl + vbyte) = pk;
        }
      }
      __syncthreads();

      // ---- issue next tile's loads; they fly under this tile's compute ----
      if (kt < qt) issue_loads((kt + 1) * KB);

      // ---- S = Q K^T ----
      f32x4 s[4];
#pragma unroll
      for (int nt = 0; nt < 4; ++nt) { s[nt][0] = 0.f; s[nt][1] = 0.f; s[nt][2] = 0.f; s[nt][3] = 0.f; }
      __builtin_amdgcn_s_setprio(1);
#pragma unroll
      for (int nt = 0; nt < 4; ++nt) {
        int row = nt * 16 + cc;
#pragma unroll
        for (int dc = 0; dc < 4; ++dc) {
          int byte = (row * 256 + dc * 64 + g * 16) ^ ((row & 7) << 4);
          bf16x8 kf = *reinterpret_cast<const bf16x8*>(Kl + byte);
          s[nt] = __builtin_amdgcn_mfma_f32_16x16x32_bf16(qf[dc], kf, s[nt], 0, 0, 0);
        }
      }
      __builtin_amdgcn_s_setprio(0);

      // ---- causal mask on diagonal tile ----
      if (kt == qt) {
#pragma unroll
        for (int nt = 0; nt < 4; ++nt)
#pragma unroll
          for (int r = 0; r < 4; ++r)
            if (nt * 16 + cc > w * 16 + g * 4 + r) s[nt][r] = -1e30f;
      }

      // ---- online softmax (row q = 4g+reg; reduce across 16 lanes of quad-group) ----
      float tmax[4];
#pragma unroll
      for (int r = 0; r < 4; ++r)
        tmax[r] = fmaxf(fmaxf(s[0][r], s[1][r]), fmaxf(s[2][r], s[3][r]));
#pragma unroll
      for (int off = 1; off < 16; off <<= 1) {
#pragma unroll
        for (int r = 0; r < 4; ++r)
          tmax[r] = fmaxf(tmax[r], __shfl_xor(tmax[r], off, 64));
      }
      float alpha[4];
#pragma unroll
      for (int r = 0; r < 4; ++r) {
        float mn = fmaxf(m_run[r], tmax[r]);
        alpha[r] = exp2f((m_run[r] - mn) * SCALE_LOG2E);
        m_run[r] = mn;
      }
      float p[4][4];
      float psum[4] = {0.f, 0.f, 0.f, 0.f};
#pragma unroll
      for (int nt = 0; nt < 4; ++nt)
#pragma unroll
        for (int r = 0; r < 4; ++r) {
          float pv = exp2f((s[nt][r] - m_run[r]) * SCALE_LOG2E);
          p[nt][r] = pv;
          psum[r] += pv;
        }
#pragma unroll
      for (int r = 0; r < 4; ++r) l_run[r] = l_run[r] * alpha[r] + psum[r];

      float aq = bcast_row(alpha, lane);
#pragma unroll
      for (int mt = 0; mt < 8; ++mt) {
        oacc[mt][0] *= aq; oacc[mt][1] *= aq; oacc[mt][2] *= aq; oacc[mt][3] *= aq;
      }

      // ---- write P tile (bf16) to wave-private LDS ----
#pragma unroll
      for (int nt = 0; nt < 4; ++nt)
#pragma unroll
        for (int r = 0; r < 4; ++r)
          *reinterpret_cast<unsigned short*>(Pl + (g * 4 + r) * 144 + (nt * 16 + cc) * 2) =
              f2bf(p[nt][r]);

      asm volatile("s_waitcnt lgkmcnt(0)" ::: "memory");
      __builtin_amdgcn_sched_barrier(0);

      // ---- O^T += Vt * P^T ----
      __builtin_amdgcn_s_setprio(1);
#pragma unroll
      for (int kc = 0; kc < 2; ++kc) {
        bf16x8 pf = *reinterpret_cast<const bf16x8*>(Pl + cc * 144 + kc * 64 + g * 16);
#pragma unroll
        for (int mt = 0; mt < 8; ++mt) {
          int d = mt * 16 + cc;
          int byte = (d * 128 + kc * 64 + g * 16) ^ (((d >> 1) & 7) << 4);
          bf16x8 vf = *reinterpret_cast<const bf16x8*>(Vl + byte);
          oacc[mt] = __builtin_amdgcn_mfma_f32_16x16x32_bf16(vf, pf, oacc[mt], 0, 0, 0);
        }
      }
      __builtin_amdgcn_s_setprio(0);
      __syncthreads();
    }

    // ---- epilogue: finish row sums, normalize, store ----
#pragma unroll
    for (int off = 1; off < 16; off <<= 1) {
#pragma unroll
      for (int r = 0; r < 4; ++r)
        l_run[r] += __shfl_xor(l_run[r], off, 64);
    }
    float Lq = bcast_row(l_run, lane);
    float inv = 1.0f / Lq;

    float* op = O + bh + (size_t)(qt * QB + w * 16 + cc) * ROWSTRIDE;
#pragma unroll
    for (int mt = 0; mt < 8; ++mt)
#pragma unroll
      for (int r = 0; r < 4; ++r)
        op[mt * 16 + g * 4 + r] = oacc[mt][r] * inv;
  }
}

extern "C" void kernel_launch(void* const* d_in, const int* in_sizes, int n_in,
                              void* d_out, int out_size, void* d_ws, size_t ws_size,
                              hipStream_t stream) {
  const float* Q = (const float*)d_in[0];
  const float* K = (const float*)d_in[1];
  const float* V = (const float*)d_in[2];
  float* O = (float*)d_out;
  dim3 grid((NQT / 2) * NH * NB);   // 512 blocks, 1D for XCD swizzle
  fattn_fwd<<<grid, dim3(256), 0, stream>>>(Q, K, V, O);
}